// Round 9
// baseline (181.884 us; speedup 1.0000x reference)
//
#include <hip/hip_runtime.h>
#include <stdint.h>

typedef __attribute__((ext_vector_type(8))) short bf16x8;
typedef __attribute__((ext_vector_type(4))) float f32x4;
typedef unsigned short u16;

__device__ __forceinline__ float bf2f(u16 b) {
    unsigned int u = ((unsigned int)b) << 16;
    return __builtin_bit_cast(float, u);
}
__device__ __forceinline__ u16 f2bf(float f) {
    unsigned int u = __builtin_bit_cast(unsigned int, f);
    u += 0x7fffu + ((u >> 16) & 1u);
    return (u16)(u >> 16);
}
__device__ __forceinline__ u16 f2bf_trunc(float f) {
    return (u16)(__builtin_bit_cast(unsigned int, f) >> 16);
}

__device__ __forceinline__ void gl2lds16(const u16* g, u16* l) {
    __builtin_amdgcn_global_load_lds(
        (const __attribute__((address_space(1))) unsigned int*)g,
        (__attribute__((address_space(3))) unsigned int*)l, 16, 0, 0);
}

// ---------------- fused prep: hs cvt + both weight transposes ----------------
__global__ __launch_bounds__(256) void prep_kernel(
    const float* __restrict__ hs, const float* __restrict__ Wqkv,
    const float* __restrict__ Wproj, u16* __restrict__ hs_bf,
    u16* __restrict__ wqkv_t, u16* __restrict__ wproj_t) {
    __shared__ float t[64][68];
    int bx = blockIdx.x, tid = threadIdx.x;
    if (bx < 4096) {
        long i = ((long)bx * 256 + tid) * 4;
        float4 v = *(const float4*)(hs + i);
        alignas(8) u16 o[4] = {f2bf(v.x), f2bf(v.y), f2bf(v.z), f2bf(v.w)};
        *(uint2*)(hs_bf + i) = *(const uint2*)o;
        return;
    }
    const float* in;
    u16* out;
    int R = 1024, C, c0, r0;
    if (bx < 4864) {
        int tt = bx - 4096;                    // 48 x 16
        C = 3072; c0 = (tt % 48) * 64; r0 = (tt / 48) * 64;
        in = Wqkv; out = wqkv_t;
    } else {
        int tt = bx - 4864;                    // 16 x 16
        C = 1024; c0 = (tt % 16) * 64; r0 = (tt / 16) * 64;
        in = Wproj; out = wproj_t;
    }
#pragma unroll
    for (int i = 0; i < 4; i++) {
        int ch = i * 256 + tid;
        int r = ch >> 4, cc = (ch & 15) * 4;
        float4 v = *(const float4*)(in + (long)(r0 + r) * C + c0 + cc);
        *(float4*)&t[r][cc] = v;
    }
    __syncthreads();
#pragma unroll
    for (int i = 0; i < 2; i++) {
        int ch = i * 256 + tid;
        int cw = ch >> 3, rr = (ch & 7) * 8;
        alignas(16) u16 tmp[8];
#pragma unroll
        for (int j = 0; j < 8; j++) tmp[j] = f2bf(t[rr + j][cw]);
        *(int4*)(out + (long)(c0 + cw) * R + r0 + rr) = *(const int4*)tmp;
    }
}

// ---------------- QKV GEMM: 128x128, BK=32, ping-pong double-buffered LDS ----------------
// grid (24, 32). Q,K -> [bh][s][64]; V -> masked V^T [bh][65][1024] (row 64 = mask)
__global__ __launch_bounds__(256) void gemm_qkv(
    const u16* __restrict__ X, const u16* __restrict__ Wt,
    const float* __restrict__ bias, const int* __restrict__ amask,
    u16* __restrict__ q_ws, u16* __restrict__ k_ws, u16* __restrict__ vt_ws) {
    const int K = 1024;
    __shared__ u16 As[2][128 * 32];
    __shared__ u16 Bs[2][128 * 32];
    const int tid = threadIdx.x;
    const int m0 = blockIdx.y * 128, n0 = blockIdx.x * 128;
    const int w = tid >> 6, lane = tid & 63, l16 = lane & 15, quad = lane >> 4;
    const int wm = (w >> 1) * 64, wn = (w & 1) * 64;

    f32x4 acc[4][4];
    const f32x4 z = {0.f, 0.f, 0.f, 0.f};
#pragma unroll
    for (int i = 0; i < 4; i++)
#pragma unroll
        for (int j = 0; j < 4; j++) acc[i][j] = z;

    auto stage = [&](int k0, int pb) {
#pragma unroll
        for (int i = 0; i < 2; i++) {
            int slot = i * 256 + tid;           // 512 granules of 16B
            int row = slot >> 2, gp = slot & 3;
            int g = gp ^ ((row >> 1) & 3);
            gl2lds16(X + (long)(m0 + row) * K + k0 + g * 8, &As[pb][slot * 8]);
            gl2lds16(Wt + (long)(n0 + row) * K + k0 + g * 8, &Bs[pb][slot * 8]);
        }
    };

    stage(0, 0);
    for (int it = 0; it < 32; it++) {
        int buf = it & 1;
        __syncthreads();                        // drains loads for tile `it` (issued 1 phase ago)
        if (it + 1 < 32) stage((it + 1) * 32, buf ^ 1);
        bf16x8 af[4], bfr[4];
#pragma unroll
        for (int mt = 0; mt < 4; mt++) {
            int row = wm + mt * 16 + l16;
            int g = quad ^ ((row >> 1) & 3);
            af[mt] = *(const bf16x8*)&As[buf][row * 32 + g * 8];
        }
#pragma unroll
        for (int nt = 0; nt < 4; nt++) {
            int row = wn + nt * 16 + l16;
            int g = quad ^ ((row >> 1) & 3);
            bfr[nt] = *(const bf16x8*)&Bs[buf][row * 32 + g * 8];
        }
#pragma unroll
        for (int mt = 0; mt < 4; mt++)
#pragma unroll
            for (int nt = 0; nt < 4; nt++)
                acc[mt][nt] = __builtin_amdgcn_mfma_f32_16x16x32_bf16(
                    af[mt], bfr[nt], acc[mt][nt], 0, 0, 0);
    }

    // scatter epilogue (block-uniform which / b)
    const int which = n0 >> 10;        // 0=Q 1=K 2=V
    const int b = m0 >> 10;
    int ncol[4]; float bv[4];
#pragma unroll
    for (int nt = 0; nt < 4; nt++) {
        ncol[nt] = n0 + wn + nt * 16 + l16;
        bv[nt] = bias[ncol[nt]];
    }
#pragma unroll
    for (int mt = 0; mt < 4; mt++) {
#pragma unroll
        for (int r = 0; r < 4; r++) {
            int m = m0 + wm + mt * 16 + quad * 4 + r;
            int s = m & 1023;
            float mk = 1.f;
            if (which == 2) mk = amask[b * 1024 + s] ? 1.f : 0.f;
#pragma unroll
            for (int nt = 0; nt < 4; nt++) {
                int e = ncol[nt] & 1023, h = e >> 6, d = e & 63;
                float val = acc[mt][nt][r] + bv[nt];
                if (which == 0)
                    q_ws[((long)(b * 16 + h) * 1024 + s) * 64 + d] = f2bf(val);
                else if (which == 1)
                    k_ws[((long)(b * 16 + h) * 1024 + s) * 64 + d] = f2bf(val);
                else
                    vt_ws[((long)(b * 16 + h) * 65 + d) * 1024 + s] = f2bf(val * mk);
            }
        }
    }
    if (which == 2) {                  // mask row for this tile's 2 heads, 128 s
        int hh = ((n0 & 1023) >> 6) + (tid >> 7);
        int s = (m0 & 1023) + (tid & 127);
        vt_ws[((long)(b * 16 + hh) * 65 + 64) * 1024 + s] =
            amask[b * 1024 + s] ? (u16)0x3F80 : (u16)0;
    }
}

// ---------------- causal flash attention (r6-verbatim) ----------------
#define PPAD 88
__global__ __launch_bounds__(256) void attn_kernel(
    const u16* __restrict__ Q, const u16* __restrict__ K,
    const u16* __restrict__ Vt, u16* __restrict__ O) {
    const int S = 1024;
    const int idx = blockIdx.x;
    const int qb = 15 - (idx >> 6);
    const int bh = idx & 63, b = bh >> 4, h = bh & 15;
    const int tid = threadIdx.x, w = tid >> 6, lane = tid & 63;
    const int l16 = lane & 15, quad = lane >> 4;
    const int q0 = qb * 64 + w * 16;

    __shared__ u16 kt[2][64 * 64];
    __shared__ u16 vt[2][80 * 64];
    __shared__ u16 p_lds[4][16][PPAD];

    const u16* Qb = Q + (long)bh * S * 64;
    const u16* Kb = K + (long)bh * S * 64;
    const u16* Vb = Vt + (long)bh * 65 * S;

    if (tid < 240) {
        int bufi = tid >= 120, rem = tid - bufi * 120;
        int row = 65 + (rem >> 3), gp = rem & 7;
        const int4 z4 = {0, 0, 0, 0};
        *(int4*)&vt[bufi][row * 64 + gp * 8] = z4;
    }

    const float C = 0.125f * 1.4426950408889634f;
    bf16x8 qf[2];
#pragma unroll
    for (int kc = 0; kc < 2; kc++) {
        bf16x8 qr = *(const bf16x8*)(Qb + (q0 + l16) * 64 + kc * 32 + quad * 8);
        bf16x8 qs;
#pragma unroll
        for (int e = 0; e < 8; e++) qs[e] = (short)f2bf(bf2f((u16)qr[e]) * C);
        qf[kc] = qs;
    }

    const f32x4 z = {0.f, 0.f, 0.f, 0.f};
    f32x4 o_acc[5];
#pragma unroll
    for (int nt = 0; nt < 5; nt++) o_acc[nt] = z;

    auto prefetch = [&](int j, int pb) {
        int4 mrow;
        if (tid < 8)
            mrow = *(const int4*)(Vb + 64 * S + j * 64 + tid * 8);
#pragma unroll
        for (int i = 0; i < 2; i++) {
            int slot = i * 256 + tid;
            int row = slot >> 3, gp = slot & 7;
            int g = gp ^ (row & 7);
            gl2lds16(Kb + (j * 64 + row) * 64 + g * 8, &kt[pb][slot * 8]);
        }
#pragma unroll
        for (int i = 0; i < 2; i++) {
            int slot = i * 256 + tid;
            int row = slot >> 3, gp = slot & 7;
            int g = gp ^ (row & 7);
            gl2lds16(Vb + (long)row * S + j * 64 + g * 8, &vt[pb][slot * 8]);
        }
        if (tid < 8)
            *(int4*)&vt[pb][64 * 64 + tid * 8] = mrow;
    };

    prefetch(0, 0);
    for (int j = 0; j <= qb; j++) {
        int buf = j & 1;
        __syncthreads();
        if (j < qb) prefetch(j + 1, buf ^ 1);

        f32x4 s_acc[4];
#pragma unroll
        for (int nt = 0; nt < 4; nt++) s_acc[nt] = z;
#pragma unroll
        for (int nt = 0; nt < 4; nt++) {
            int row = nt * 16 + l16;
#pragma unroll
            for (int kc = 0; kc < 2; kc++) {
                int g = (kc * 4 + quad) ^ (row & 7);
                bf16x8 kf = *(const bf16x8*)&kt[buf][row * 64 + g * 8];
                s_acc[nt] = __builtin_amdgcn_mfma_f32_16x16x32_bf16(qf[kc], kf, s_acc[nt], 0, 0, 0);
            }
        }
        float p[4][4];
#pragma unroll
        for (int nt = 0; nt < 4; nt++)
#pragma unroll
            for (int r = 0; r < 4; r++) p[nt][r] = exp2f(s_acc[nt][r]);
        if (j == qb) {
#pragma unroll
            for (int nt = 0; nt < 4; nt++) {
                int key = j * 64 + nt * 16 + l16;
#pragma unroll
                for (int r = 0; r < 4; r++)
                    if (key > q0 + quad * 4 + r) p[nt][r] = 0.f;
            }
        }
#pragma unroll
        for (int nt = 0; nt < 4; nt++)
#pragma unroll
            for (int r = 0; r < 4; r++)
                p_lds[w][quad * 4 + r][nt * 16 + l16] = f2bf_trunc(p[nt][r]);
        bf16x8 pf[2];
#pragma unroll
        for (int kc = 0; kc < 2; kc++)
            pf[kc] = *(const bf16x8*)&p_lds[w][l16][kc * 32 + quad * 8];
#pragma unroll
        for (int nt = 0; nt < 5; nt++) {
            int row = nt * 16 + l16;
#pragma unroll
            for (int kc = 0; kc < 2; kc++) {
                int g = (kc * 4 + quad) ^ (row & 7);
                bf16x8 vf = *(const bf16x8*)&vt[buf][row * 64 + g * 8];
                o_acc[nt] = __builtin_amdgcn_mfma_f32_16x16x32_bf16(pf[kc], vf, o_acc[nt], 0, 0, 0);
            }
        }
    }
#pragma unroll
    for (int r = 0; r < 4; r++) {
        float l = __shfl(o_acc[4][r], lane & 48, 64);
        float inv = 1.0f / l;
        int qg = q0 + quad * 4 + r;
#pragma unroll
        for (int nt = 0; nt < 4; nt++)
            O[((long)(b * S + qg)) * 1024 + h * 64 + nt * 16 + l16] = f2bf(o_acc[nt][r] * inv);
    }
}

// ---------------- proj GEMM: 128x64, BK=32, ping-pong dbuf, grid (16,32) ----------------
__global__ __launch_bounds__(256) void gemm_proj(
    const u16* __restrict__ X, const u16* __restrict__ Wt,
    const float* __restrict__ bias, float* __restrict__ outF) {
    const int K = 1024, N = 1024;
    __shared__ u16 As[2][128 * 32];
    __shared__ u16 Bs[2][64 * 32];
    const int tid = threadIdx.x;
    const int m0 = blockIdx.y * 128, n0 = blockIdx.x * 64;
    const int w = tid >> 6, lane = tid & 63, l16 = lane & 15, quad = lane >> 4;
    const int wm = (w >> 1) * 64, wn = (w & 1) * 32;

    f32x4 acc[4][2];
    const f32x4 z = {0.f, 0.f, 0.f, 0.f};
#pragma unroll
    for (int i = 0; i < 4; i++)
#pragma unroll
        for (int j = 0; j < 2; j++) acc[i][j] = z;

    auto stage = [&](int k0, int pb) {
#pragma unroll
        for (int i = 0; i < 2; i++) {
            int slot = i * 256 + tid;
            int row = slot >> 2, gp = slot & 3;
            int g = gp ^ ((row >> 1) & 3);
            gl2lds16(X + (long)(m0 + row) * K + k0 + g * 8, &As[pb][slot * 8]);
        }
        {
            int slot = tid;                     // 256 granules for 64 rows
            int row = slot >> 2, gp = slot & 3;
            int g = gp ^ ((row >> 1) & 3);
            gl2lds16(Wt + (long)(n0 + row) * K + k0 + g * 8, &Bs[pb][slot * 8]);
        }
    };

    stage(0, 0);
    for (int it = 0; it < 32; it++) {
        int buf = it & 1;
        __syncthreads();
        if (it + 1 < 32) stage((it + 1) * 32, buf ^ 1);
        bf16x8 af[4], bfr[2];
#pragma unroll
        for (int mt = 0; mt < 4; mt++) {
            int row = wm + mt * 16 + l16;
            int g = quad ^ ((row >> 1) & 3);
            af[mt] = *(const bf16x8*)&As[buf][row * 32 + g * 8];
        }
#pragma unroll
        for (int nt = 0; nt < 2; nt++) {
            int row = wn + nt * 16 + l16;
            int g = quad ^ ((row >> 1) & 3);
            bfr[nt] = *(const bf16x8*)&Bs[buf][row * 32 + g * 8];
        }
#pragma unroll
        for (int mt = 0; mt < 4; mt++)
#pragma unroll
            for (int nt = 0; nt < 2; nt++)
                acc[mt][nt] = __builtin_amdgcn_mfma_f32_16x16x32_bf16(
                    af[mt], bfr[nt], acc[mt][nt], 0, 0, 0);
    }
#pragma unroll
    for (int nt = 0; nt < 2; nt++) {
        int n = n0 + wn + nt * 16 + l16;
        float bias_v = bias[n];
#pragma unroll
        for (int mt = 0; mt < 4; mt++)
#pragma unroll
            for (int r = 0; r < 4; r++) {
                int m = m0 + wm + mt * 16 + quad * 4 + r;
                outF[(long)m * N + n] = acc[mt][nt][r] + bias_v;
            }
    }
}

extern "C" void kernel_launch(void* const* d_in, const int* in_sizes, int n_in,
                              void* d_out, int out_size, void* d_ws, size_t ws_size,
                              hipStream_t stream) {
    const float* hs    = (const float*)d_in[0];
    const int*   amask = (const int*)d_in[1];
    const float* Wqkv  = (const float*)d_in[2];
    const float* bqkv  = (const float*)d_in[3];
    const float* Wproj = (const float*)d_in[4];
    const float* bproj = (const float*)d_in[5];
    float* out = (float*)d_out;

    const long ME = 4096L * 1024L;
    const long VT = 65L * 1024L * 64L;
    size_t need = (3072L * 1024 + ME + 1024L * 1024 + 2 * ME + VT) * 2;
    if (ws_size < need) return;

    u16* wqkv_t  = (u16*)d_ws;
    u16* hs_bf   = wqkv_t + 3072L * 1024;
    u16* wproj_t = hs_bf + ME;
    u16* q_ws    = wproj_t + 1024L * 1024;
    u16* k_ws    = q_ws + ME;
    u16* vt_ws   = k_ws + ME;
    u16* attn_out= (u16*)d_ws;                 // overlays wqkv_t+hs_bf

    dim3 blk(256);
    prep_kernel<<<dim3(5120), blk, 0, stream>>>(hs, Wqkv, Wproj, hs_bf, wqkv_t, wproj_t);
    gemm_qkv<<<dim3(24, 32), blk, 0, stream>>>(hs_bf, wqkv_t, bqkv, amask, q_ws, k_ws, vt_ws);
    attn_kernel<<<dim3(1024), blk, 0, stream>>>(q_ws, k_ws, vt_ws, attn_out);
    gemm_proj<<<dim3(16, 32), blk, 0, stream>>>(attn_out, wproj_t, bproj, out);
}

// Round 10
// 167.502 us; speedup vs baseline: 1.0859x; 1.0859x over previous
//
#include <hip/hip_runtime.h>
#include <stdint.h>

typedef __attribute__((ext_vector_type(8))) short bf16x8;
typedef __attribute__((ext_vector_type(4))) float f32x4;
typedef unsigned short u16;

__device__ __forceinline__ float bf2f(u16 b) {
    unsigned int u = ((unsigned int)b) << 16;
    return __builtin_bit_cast(float, u);
}
__device__ __forceinline__ u16 f2bf(float f) {
    unsigned int u = __builtin_bit_cast(unsigned int, f);
    u += 0x7fffu + ((u >> 16) & 1u);
    return (u16)(u >> 16);
}
__device__ __forceinline__ u16 f2bf_trunc(float f) {
    return (u16)(__builtin_bit_cast(unsigned int, f) >> 16);
}

__device__ __forceinline__ void gl2lds16(const u16* g, u16* l) {
    __builtin_amdgcn_global_load_lds(
        (const __attribute__((address_space(1))) unsigned int*)g,
        (__attribute__((address_space(3))) unsigned int*)l, 16, 0, 0);
}

// ---------------- fused prep: hs cvt + both weight transposes ----------------
__global__ __launch_bounds__(256) void prep_kernel(
    const float* __restrict__ hs, const float* __restrict__ Wqkv,
    const float* __restrict__ Wproj, u16* __restrict__ hs_bf,
    u16* __restrict__ wqkv_t, u16* __restrict__ wproj_t) {
    __shared__ float t[64][68];
    int bx = blockIdx.x, tid = threadIdx.x;
    if (bx < 4096) {
        long i = ((long)bx * 256 + tid) * 4;
        float4 v = *(const float4*)(hs + i);
        alignas(8) u16 o[4] = {f2bf(v.x), f2bf(v.y), f2bf(v.z), f2bf(v.w)};
        *(uint2*)(hs_bf + i) = *(const uint2*)o;
        return;
    }
    const float* in;
    u16* out;
    int R = 1024, C, c0, r0;
    if (bx < 4864) {
        int tt = bx - 4096;                    // 48 x 16
        C = 3072; c0 = (tt % 48) * 64; r0 = (tt / 48) * 64;
        in = Wqkv; out = wqkv_t;
    } else {
        int tt = bx - 4864;                    // 16 x 16
        C = 1024; c0 = (tt % 16) * 64; r0 = (tt / 16) * 64;
        in = Wproj; out = wproj_t;
    }
#pragma unroll
    for (int i = 0; i < 4; i++) {
        int ch = i * 256 + tid;
        int r = ch >> 4, cc = (ch & 15) * 4;
        float4 v = *(const float4*)(in + (long)(r0 + r) * C + c0 + cc);
        *(float4*)&t[r][cc] = v;
    }
    __syncthreads();
#pragma unroll
    for (int i = 0; i < 2; i++) {
        int ch = i * 256 + tid;
        int cw = ch >> 3, rr = (ch & 7) * 8;
        alignas(16) u16 tmp[8];
#pragma unroll
        for (int j = 0; j < 8; j++) tmp[j] = f2bf(t[rr + j][cw]);
        *(int4*)(out + (long)(c0 + cw) * R + r0 + rr) = *(const int4*)tmp;
    }
}

// ---------------- QKV GEMM: 128x128, BK=64, single-buffer LDS (32 KB, 3 blk/CU) ----------------
// grid (24, 32). Q,K -> [bh][s][64]; V -> masked V^T [bh][65][1024] (row 64 = mask)
__global__ __launch_bounds__(256) void gemm_qkv(
    const u16* __restrict__ X, const u16* __restrict__ Wt,
    const float* __restrict__ bias, const int* __restrict__ amask,
    u16* __restrict__ q_ws, u16* __restrict__ k_ws, u16* __restrict__ vt_ws) {
    const int K = 1024;
    __shared__ u16 As[128 * 64];       // [row][k], 8 granules/row, XOR-swizzled
    __shared__ u16 Bs[128 * 64];
    const int tid = threadIdx.x;
    const int m0 = blockIdx.y * 128, n0 = blockIdx.x * 128;
    const int w = tid >> 6, lane = tid & 63, l16 = lane & 15, quad = lane >> 4;
    const int wm = (w >> 1) * 64, wn = (w & 1) * 64;

    f32x4 acc[4][4];
    const f32x4 z = {0.f, 0.f, 0.f, 0.f};
#pragma unroll
    for (int i = 0; i < 4; i++)
#pragma unroll
        for (int j = 0; j < 4; j++) acc[i][j] = z;

    for (int it = 0; it < 16; it++) {
        const int k0 = it * 64;
        if (it) __syncthreads();               // readers of previous tile done
#pragma unroll
        for (int i = 0; i < 4; i++) {          // As: 1024 granules of 16B
            int slot = i * 256 + tid;
            int row = slot >> 3, gp = slot & 7;
            int g = gp ^ (row & 7);
            gl2lds16(X + (long)(m0 + row) * K + k0 + g * 8, &As[slot * 8]);
        }
#pragma unroll
        for (int i = 0; i < 4; i++) {          // Bs: 1024 granules
            int slot = i * 256 + tid;
            int row = slot >> 3, gp = slot & 7;
            int g = gp ^ (row & 7);
            gl2lds16(Wt + (long)(n0 + row) * K + k0 + g * 8, &Bs[slot * 8]);
        }
        __syncthreads();                       // data ready
#pragma unroll
        for (int kc = 0; kc < 2; kc++) {
            bf16x8 af[4], bfr[4];
#pragma unroll
            for (int mt = 0; mt < 4; mt++) {
                int row = wm + mt * 16 + l16;
                int g = (kc * 4 + quad) ^ (row & 7);
                af[mt] = *(const bf16x8*)&As[row * 64 + g * 8];
            }
#pragma unroll
            for (int nt = 0; nt < 4; nt++) {
                int row = wn + nt * 16 + l16;
                int g = (kc * 4 + quad) ^ (row & 7);
                bfr[nt] = *(const bf16x8*)&Bs[row * 64 + g * 8];
            }
#pragma unroll
            for (int mt = 0; mt < 4; mt++)
#pragma unroll
                for (int nt = 0; nt < 4; nt++)
                    acc[mt][nt] = __builtin_amdgcn_mfma_f32_16x16x32_bf16(
                        af[mt], bfr[nt], acc[mt][nt], 0, 0, 0);
        }
    }

    // scatter epilogue (block-uniform which / b)
    const int which = n0 >> 10;        // 0=Q 1=K 2=V
    const int b = m0 >> 10;
    int ncol[4]; float bv[4];
#pragma unroll
    for (int nt = 0; nt < 4; nt++) {
        ncol[nt] = n0 + wn + nt * 16 + l16;
        bv[nt] = bias[ncol[nt]];
    }
#pragma unroll
    for (int mt = 0; mt < 4; mt++) {
#pragma unroll
        for (int r = 0; r < 4; r++) {
            int m = m0 + wm + mt * 16 + quad * 4 + r;
            int s = m & 1023;
            float mk = 1.f;
            if (which == 2) mk = amask[b * 1024 + s] ? 1.f : 0.f;
#pragma unroll
            for (int nt = 0; nt < 4; nt++) {
                int e = ncol[nt] & 1023, h = e >> 6, d = e & 63;
                float val = acc[mt][nt][r] + bv[nt];
                if (which == 0)
                    q_ws[((long)(b * 16 + h) * 1024 + s) * 64 + d] = f2bf(val);
                else if (which == 1)
                    k_ws[((long)(b * 16 + h) * 1024 + s) * 64 + d] = f2bf(val);
                else
                    vt_ws[((long)(b * 16 + h) * 65 + d) * 1024 + s] = f2bf(val * mk);
            }
        }
    }
    if (which == 2) {                  // mask row for this tile's 2 heads, 128 s
        int hh = ((n0 & 1023) >> 6) + (tid >> 7);
        int s = (m0 & 1023) + (tid & 127);
        vt_ws[((long)(b * 16 + hh) * 65 + 64) * 1024 + s] =
            amask[b * 1024 + s] ? (u16)0x3F80 : (u16)0;
    }
}

// ---------------- causal flash attention (r6-verbatim) ----------------
#define PPAD 88
__global__ __launch_bounds__(256) void attn_kernel(
    const u16* __restrict__ Q, const u16* __restrict__ K,
    const u16* __restrict__ Vt, u16* __restrict__ O) {
    const int S = 1024;
    const int idx = blockIdx.x;
    const int qb = 15 - (idx >> 6);
    const int bh = idx & 63, b = bh >> 4, h = bh & 15;
    const int tid = threadIdx.x, w = tid >> 6, lane = tid & 63;
    const int l16 = lane & 15, quad = lane >> 4;
    const int q0 = qb * 64 + w * 16;

    __shared__ u16 kt[2][64 * 64];
    __shared__ u16 vt[2][80 * 64];
    __shared__ u16 p_lds[4][16][PPAD];

    const u16* Qb = Q + (long)bh * S * 64;
    const u16* Kb = K + (long)bh * S * 64;
    const u16* Vb = Vt + (long)bh * 65 * S;

    if (tid < 240) {
        int bufi = tid >= 120, rem = tid - bufi * 120;
        int row = 65 + (rem >> 3), gp = rem & 7;
        const int4 z4 = {0, 0, 0, 0};
        *(int4*)&vt[bufi][row * 64 + gp * 8] = z4;
    }

    const float C = 0.125f * 1.4426950408889634f;
    bf16x8 qf[2];
#pragma unroll
    for (int kc = 0; kc < 2; kc++) {
        bf16x8 qr = *(const bf16x8*)(Qb + (q0 + l16) * 64 + kc * 32 + quad * 8);
        bf16x8 qs;
#pragma unroll
        for (int e = 0; e < 8; e++) qs[e] = (short)f2bf(bf2f((u16)qr[e]) * C);
        qf[kc] = qs;
    }

    const f32x4 z = {0.f, 0.f, 0.f, 0.f};
    f32x4 o_acc[5];
#pragma unroll
    for (int nt = 0; nt < 5; nt++) o_acc[nt] = z;

    auto prefetch = [&](int j, int pb) {
        int4 mrow;
        if (tid < 8)
            mrow = *(const int4*)(Vb + 64 * S + j * 64 + tid * 8);
#pragma unroll
        for (int i = 0; i < 2; i++) {
            int slot = i * 256 + tid;
            int row = slot >> 3, gp = slot & 7;
            int g = gp ^ (row & 7);
            gl2lds16(Kb + (j * 64 + row) * 64 + g * 8, &kt[pb][slot * 8]);
        }
#pragma unroll
        for (int i = 0; i < 2; i++) {
            int slot = i * 256 + tid;
            int row = slot >> 3, gp = slot & 7;
            int g = gp ^ (row & 7);
            gl2lds16(Vb + (long)row * S + j * 64 + g * 8, &vt[pb][slot * 8]);
        }
        if (tid < 8)
            *(int4*)&vt[pb][64 * 64 + tid * 8] = mrow;
    };

    prefetch(0, 0);
    for (int j = 0; j <= qb; j++) {
        int buf = j & 1;
        __syncthreads();
        if (j < qb) prefetch(j + 1, buf ^ 1);

        f32x4 s_acc[4];
#pragma unroll
        for (int nt = 0; nt < 4; nt++) s_acc[nt] = z;
#pragma unroll
        for (int nt = 0; nt < 4; nt++) {
            int row = nt * 16 + l16;
#pragma unroll
            for (int kc = 0; kc < 2; kc++) {
                int g = (kc * 4 + quad) ^ (row & 7);
                bf16x8 kf = *(const bf16x8*)&kt[buf][row * 64 + g * 8];
                s_acc[nt] = __builtin_amdgcn_mfma_f32_16x16x32_bf16(qf[kc], kf, s_acc[nt], 0, 0, 0);
            }
        }
        float p[4][4];
#pragma unroll
        for (int nt = 0; nt < 4; nt++)
#pragma unroll
            for (int r = 0; r < 4; r++) p[nt][r] = exp2f(s_acc[nt][r]);
        if (j == qb) {
#pragma unroll
            for (int nt = 0; nt < 4; nt++) {
                int key = j * 64 + nt * 16 + l16;
#pragma unroll
                for (int r = 0; r < 4; r++)
                    if (key > q0 + quad * 4 + r) p[nt][r] = 0.f;
            }
        }
#pragma unroll
        for (int nt = 0; nt < 4; nt++)
#pragma unroll
            for (int r = 0; r < 4; r++)
                p_lds[w][quad * 4 + r][nt * 16 + l16] = f2bf_trunc(p[nt][r]);
        bf16x8 pf[2];
#pragma unroll
        for (int kc = 0; kc < 2; kc++)
            pf[kc] = *(const bf16x8*)&p_lds[w][l16][kc * 32 + quad * 8];
#pragma unroll
        for (int nt = 0; nt < 5; nt++) {
            int row = nt * 16 + l16;
#pragma unroll
            for (int kc = 0; kc < 2; kc++) {
                int g = (kc * 4 + quad) ^ (row & 7);
                bf16x8 vf = *(const bf16x8*)&vt[buf][row * 64 + g * 8];
                o_acc[nt] = __builtin_amdgcn_mfma_f32_16x16x32_bf16(pf[kc], vf, o_acc[nt], 0, 0, 0);
            }
        }
    }
#pragma unroll
    for (int r = 0; r < 4; r++) {
        float l = __shfl(o_acc[4][r], lane & 48, 64);
        float inv = 1.0f / l;
        int qg = q0 + quad * 4 + r;
#pragma unroll
        for (int nt = 0; nt < 4; nt++)
            O[((long)(b * S + qg)) * 1024 + h * 64 + nt * 16 + l16] = f2bf(o_acc[nt][r] * inv);
    }
}

// ---------------- proj GEMM: 64x64 tile, BK=64, grid (16,64) = 4 blocks/CU ----------------
__global__ __launch_bounds__(256) void gemm_proj(
    const u16* __restrict__ X, const u16* __restrict__ Wt,
    const float* __restrict__ bias, float* __restrict__ outF) {
    const int K = 1024, N = 1024;
    __shared__ u16 As[64 * 64];
    __shared__ u16 Bs[64 * 64];
    const int tid = threadIdx.x;
    const int m0 = blockIdx.y * 64, n0 = blockIdx.x * 64;
    const int w = tid >> 6, lane = tid & 63, l16 = lane & 15, quad = lane >> 4;
    const int wm = (w >> 1) * 32, wn = (w & 1) * 32;

    f32x4 acc[2][2];
    const f32x4 z = {0.f, 0.f, 0.f, 0.f};
#pragma unroll
    for (int i = 0; i < 2; i++)
#pragma unroll
        for (int j = 0; j < 2; j++) acc[i][j] = z;

    for (int k0 = 0; k0 < K; k0 += 64) {
        if (k0) __syncthreads();
#pragma unroll
        for (int i = 0; i < 2; i++) {
            int slot = i * 256 + tid;
            int row = slot >> 3, gp = slot & 7;
            int g = gp ^ (row & 7);
            gl2lds16(X + (long)(m0 + row) * K + k0 + g * 8, &As[slot * 8]);
            gl2lds16(Wt + (long)(n0 + row) * K + k0 + g * 8, &Bs[slot * 8]);
        }
        __syncthreads();
#pragma unroll
        for (int kc = 0; kc < 2; kc++) {
            bf16x8 af[2], bfr[2];
#pragma unroll
            for (int mt = 0; mt < 2; mt++) {
                int row = wm + mt * 16 + l16;
                int g = (kc * 4 + quad) ^ (row & 7);
                af[mt] = *(const bf16x8*)&As[row * 64 + g * 8];
            }
#pragma unroll
            for (int nt = 0; nt < 2; nt++) {
                int row = wn + nt * 16 + l16;
                int g = (kc * 4 + quad) ^ (row & 7);
                bfr[nt] = *(const bf16x8*)&Bs[row * 64 + g * 8];
            }
#pragma unroll
            for (int mt = 0; mt < 2; mt++)
#pragma unroll
                for (int nt = 0; nt < 2; nt++)
                    acc[mt][nt] = __builtin_amdgcn_mfma_f32_16x16x32_bf16(
                        af[mt], bfr[nt], acc[mt][nt], 0, 0, 0);
        }
    }
#pragma unroll
    for (int nt = 0; nt < 2; nt++) {
        int n = n0 + wn + nt * 16 + l16;
        float bias_v = bias[n];
#pragma unroll
        for (int mt = 0; mt < 2; mt++)
#pragma unroll
            for (int r = 0; r < 4; r++) {
                int m = m0 + wm + mt * 16 + quad * 4 + r;
                outF[(long)m * N + n] = acc[mt][nt][r] + bias_v;
            }
    }
}

extern "C" void kernel_launch(void* const* d_in, const int* in_sizes, int n_in,
                              void* d_out, int out_size, void* d_ws, size_t ws_size,
                              hipStream_t stream) {
    const float* hs    = (const float*)d_in[0];
    const int*   amask = (const int*)d_in[1];
    const float* Wqkv  = (const float*)d_in[2];
    const float* bqkv  = (const float*)d_in[3];
    const float* Wproj = (const float*)d_in[4];
    const float* bproj = (const float*)d_in[5];
    float* out = (float*)d_out;

    const long ME = 4096L * 1024L;
    const long VT = 65L * 1024L * 64L;
    size_t need = (3072L * 1024 + ME + 1024L * 1024 + 2 * ME + VT) * 2;
    if (ws_size < need) return;

    u16* wqkv_t  = (u16*)d_ws;
    u16* hs_bf   = wqkv_t + 3072L * 1024;
    u16* wproj_t = hs_bf + ME;
    u16* q_ws    = wproj_t + 1024L * 1024;
    u16* k_ws    = q_ws + ME;
    u16* vt_ws   = k_ws + ME;
    u16* attn_out= (u16*)d_ws;                 // overlays wqkv_t+hs_bf

    dim3 blk(256);
    prep_kernel<<<dim3(5120), blk, 0, stream>>>(hs, Wqkv, Wproj, hs_bf, wqkv_t, wproj_t);
    gemm_qkv<<<dim3(24, 32), blk, 0, stream>>>(hs_bf, wqkv_t, bqkv, amask, q_ws, k_ws, vt_ws);
    attn_kernel<<<dim3(1024), blk, 0, stream>>>(q_ws, k_ws, vt_ws, attn_out);
    gemm_proj<<<dim3(16, 64), blk, 0, stream>>>(attn_out, wproj_t, bproj, out);
}